// Round 5
// baseline (244.607 us; speedup 1.0000x reference)
//
#include <hip/hip_runtime.h>

// Problem constants: B=4, R=16384, S=96
#define NRAYS 65536
#define NS    96
#define NI    95

// Output layout (FP32, outputs concatenated flat in return order):
//   composite_rgb   : [0,        196608)
//   composite_depth : [196608,   262144)
//   weights         : [262144,   6488064)
//   composite_point : [6488064,  6684672)
//   tau             : [6684672,  6750208)
#define OFF_RGB   0
#define OFF_DEPTH 196608
#define OFF_W     262144
#define OFF_PT    6488064
#define OFF_TAU   6684672

// ---------------------------------------------------------------------------
// Global depth min/max. depths are jnp.sort()ed along the sample axis by
// construction, so global min = min over rays of sample 0, global max = max
// over rays of sample 95. Max encoded as atomicMin of ~bits (depths >= 0),
// so both ws slots init 0xFFFFFFFF -> single 8-byte memset.
// ---------------------------------------------------------------------------
__global__ void depth_minmax_sorted(const float* __restrict__ deps, unsigned* ws) {
    const int t = blockIdx.x * blockDim.x + threadIdx.x;   // grid covers exactly NRAYS
    float lo = deps[(size_t)t * NS];
    float hi = deps[(size_t)t * NS + (NS - 1)];
    #pragma unroll
    for (int off = 32; off; off >>= 1) {
        lo = fminf(lo, __shfl_xor(lo, off, 64));
        hi = fmaxf(hi, __shfl_xor(hi, off, 64));
    }
    if ((threadIdx.x & 63) == 0) {
        atomicMin(&ws[0], __float_as_uint(lo));
        atomicMin(&ws[1], ~__float_as_uint(hi));   // max via inverted-bit min
    }
}

__device__ __forceinline__ float softplus_fast(float x) {
    // softplus = max(x,0) + log(1 + exp(-|x|)); __logf/__expf are single
    // v_log/v_exp instrs (~1e-6 rel err; tolerance headroom ~6x).
    return fmaxf(x, 0.0f) + __logf(1.0f + __expf(-fabsf(x)));
}

// ---------------------------------------------------------------------------
// R5. R4 post-mortem: VGPR_Count=36 proved the compiler SANK the up-front
// load burst back into the phases (48 floats of in-flight data cannot live
// in 36 VGPRs) -- the MLP experiment never ran. Two independent fixes here:
//  * keep-alive asm consuming one element of each of the 16 load instrs,
//    placed before phase A: data-dependence forces issue-all-then-wait-once;
//    phases then run with zero further vmem waits. (Verify: VGPR ~70-90.)
//  * bijective XCD swizzle (4096 wgs, %8==0): each XCD gets a contiguous
//    512-block (~50 MB) slice of the input streams -> dense per-XCD L2/DRAM
//    address streams instead of 12-KB interleave across 8 XCDs.
// Everything else identical to verified R4 (wave-private LDS, no barriers,
// direct dword weight scatter -- R1/R2/R4-proven WRITE ~= 27 MB).
// ---------------------------------------------------------------------------
__launch_bounds__(256, 5)
__global__ void raymarch(const float* __restrict__ colors,
                         const float* __restrict__ dens,
                         const float* __restrict__ deps,
                         const float* __restrict__ coords,
                         const int* __restrict__ wbp,
                         const unsigned* __restrict__ mm,
                         float* __restrict__ out) {
    __shared__ float sbuf[4 * 1152];   // 18432 B: one 1152-float region per wave

    const int tid  = threadIdx.x;
    const int lane = tid & 63;
    const int wv   = tid >> 6;                    // wave in block (0..3)
    const int sub  = lane & 15;                   // position within ray group
    const int r4   = lane >> 4;                   // ray within wave (0..3)

    // bijective XCD-aware block swizzle: 4096 % 8 == 0 -> chunks of 512
    const int blk  = (blockIdx.x & 7) * (int)(gridDim.x >> 3) + (blockIdx.x >> 3);
    const int g    = blk * 16 + wv * 4 + r4;      // global ray id

    // ---- issue ALL global loads up front (max MLP), fully coalesced ----
    const size_t rb0 = (size_t)blk * 16 + wv * 4;  // first ray of wave
    const float2* dg2 = (const float2*)(deps + rb0 * NS);
    const float2* ng2 = (const float2*)(dens + rb0 * NS);
    float2 dr[3], nr[3];
    #pragma unroll
    for (int k = 0; k < 3; ++k) dr[k] = dg2[lane + 64 * k];   // 384 floats
    #pragma unroll
    for (int k = 0; k < 3; ++k) nr[k] = ng2[lane + 64 * k];
    const float4* cg4 = (const float4*)(colors + rb0 * NS * 3);
    const float4* pg4 = (const float4*)(coords + rb0 * NS * 3);
    float4 cr[4], pr[4];
    #pragma unroll
    for (int k = 0; k < 4; ++k) cr[k] = cg4[lane + 64 * k];   // 1024 floats
    float2 crt = ((const float2*)(colors + rb0 * NS * 3 + 1024))[lane];  // +128
    #pragma unroll
    for (int k = 0; k < 4; ++k) pr[k] = pg4[lane + 64 * k];
    float2 prt = ((const float2*)(coords + rb0 * NS * 3 + 1024))[lane];

    // Keep-alive: consuming one element of each load instruction forces all
    // 16 loads to be issued before this point and completed here (single
    // vmcnt drain). Compiler cannot split a dwordx2/dwordx4, so one element
    // pins the whole instruction. This is what R4 failed to guarantee.
    asm volatile("" ::
        "v"(dr[0].x), "v"(dr[1].x), "v"(dr[2].x),
        "v"(nr[0].x), "v"(nr[1].x), "v"(nr[2].x),
        "v"(cr[0].x), "v"(cr[1].x), "v"(cr[2].x), "v"(cr[3].x), "v"(crt.x),
        "v"(pr[0].x), "v"(pr[1].x), "v"(pr[2].x), "v"(pr[3].x), "v"(prt.x));

    float* wreg = sbuf + wv * 1152;    // this wave's private LDS region

    // ---- phase A: stage d+n (wave-private, no barrier), read slices ----
    {
        float2* s2 = (float2*)wreg;
        #pragma unroll
        for (int k = 0; k < 3; ++k) s2[lane + 64 * k] = dr[k];        // d: [0,384)
        #pragma unroll
        for (int k = 0; k < 3; ++k) s2[192 + lane + 64 * k] = nr[k];  // n: [384,768)
    }
    float d[6], n[6], d6, n6;
    {
        const float2* qd = (const float2*)(wreg + r4 * 96 + 6 * sub);
        const float2* qn = (const float2*)(wreg + 384 + r4 * 96 + 6 * sub);
        #pragma unroll
        for (int j = 0; j < 3; ++j) { float2 v = qd[j]; d[2*j] = v.x; d[2*j+1] = v.y; }
        #pragma unroll
        for (int j = 0; j < 3; ++j) { float2 v = qn[j]; n[2*j] = v.x; n[2*j+1] = v.y; }
        const int noff = (sub < 15) ? 6 * (sub + 1) : 0;   // dummy for sub 15
        d6 = wreg[r4 * 96 + noff];
        n6 = wreg[384 + r4 * 96 + noff];
    }

    // ---- phase B: stage colors into the SAME region, read slices ----
    float4* s4 = (float4*)wreg;
    #pragma unroll
    for (int k = 0; k < 4; ++k) s4[lane + 64 * k] = cr[k];
    ((float2*)wreg)[512 + lane] = crt;                     // floats [1024,1152)
    float c[18], cn0, cn1, cn2;
    {
        const float2* q = (const float2*)(wreg + r4 * 288 + 18 * sub);
        #pragma unroll
        for (int j = 0; j < 9; ++j) { float2 v = q[j]; c[2*j] = v.x; c[2*j+1] = v.y; }
        const int noff = (sub < 15) ? 18 * (sub + 1) : 0;
        cn0 = wreg[r4 * 288 + noff + 0];
        cn1 = wreg[r4 * 288 + noff + 1];
        cn2 = wreg[r4 * 288 + noff + 2];
    }

    // ---- phase C: stage coords into the SAME region, read slices ----
    #pragma unroll
    for (int k = 0; k < 4; ++k) s4[lane + 64 * k] = pr[k];
    ((float2*)wreg)[512 + lane] = prt;
    float p[18], pn0, pn1, pn2;
    {
        const float2* q = (const float2*)(wreg + r4 * 288 + 18 * sub);
        #pragma unroll
        for (int j = 0; j < 9; ++j) { float2 v = q[j]; p[2*j] = v.x; p[2*j+1] = v.y; }
        const int noff = (sub < 15) ? 18 * (sub + 1) : 0;
        pn0 = wreg[r4 * 288 + noff + 0];
        pn1 = wreg[r4 * 288 + noff + 1];
        pn2 = wreg[r4 * 288 + noff + 2];
    }

    // ---- per-interval alpha / transmittance factor (interval 95 invalid) ----
    float a[6], f[6];
    #pragma unroll
    for (int i = 0; i < 6; ++i) {
        float dn1 = (i < 5) ? d[i+1] : d6;
        float nn1 = (i < 5) ? n[i+1] : n6;
        float E = __expf(-softplus_fast(0.5f * (n[i] + nn1)) * (dn1 - d[i]));
        const bool valid = (i < 5) || (sub < 15);    // compile-time except i==5
        a[i] = valid ? (1.0f - E) : 0.0f;
        f[i] = valid ? (E + 1e-10f) : 1.0f;
    }

    // ---- inclusive scan of per-lane factor product over the 16-lane group ----
    float incl = ((f[0] * f[1]) * (f[2] * f[3])) * (f[4] * f[5]);
    #pragma unroll
    for (int off = 1; off < 16; off <<= 1) {
        float t = __shfl_up(incl, off, 16);
        if (sub >= off) incl *= t;
    }
    float excl = __shfl_up(incl, 1, 16);
    if (sub == 0) excl = 1.0f;

    // ---- weights (direct scatter store, L2-merged) + composite partials ----
    float acc[8];
    #pragma unroll
    for (int k = 0; k < 8; ++k) acc[k] = 0.0f;
    float t = excl;          // t == trans[6*sub + i] at top of iteration i
    float tauc = 0.0f;
    const size_t wb = (size_t)OFF_W + (size_t)g * NI + 6 * sub;
    #pragma unroll
    for (int i = 0; i < 6; ++i) {
        float w = a[i] * t;
        if (i < 5 || sub < 15) out[wb + i] = w;      // weights output
        float dn1 = (i < 5) ? d[i+1] : d6;
        float dm  = 0.5f * (d[i] + dn1);
        float cmx = 0.5f * (c[3*i+0] + ((i < 5) ? c[3*i+3] : cn0));
        float cmy = 0.5f * (c[3*i+1] + ((i < 5) ? c[3*i+4] : cn1));
        float cmz = 0.5f * (c[3*i+2] + ((i < 5) ? c[3*i+5] : cn2));
        float pmx = 0.5f * (p[3*i+0] + ((i < 5) ? p[3*i+3] : pn0));
        float pmy = 0.5f * (p[3*i+1] + ((i < 5) ? p[3*i+4] : pn1));
        float pmz = 0.5f * (p[3*i+2] + ((i < 5) ? p[3*i+5] : pn2));
        acc[0] += w * cmx;  acc[1] += w * cmy;  acc[2] += w * cmz;
        acc[3] += w * pmx;  acc[4] += w * pmy;  acc[5] += w * pmz;
        acc[6] += w * dm;   acc[7] += w;
        if (i == 4) tauc = t;      // lane sub==15, i==4: t == trans[94] == tau
        t *= f[i];
    }
    float tau = __shfl(tauc, (lane & 48) | 15, 64);

    // ---- reduce 8 accumulators across the 16-lane group (4 butterfly steps) ----
    #pragma unroll
    for (int k = 0; k < 8; ++k) {
        #pragma unroll
        for (int off = 1; off < 16; off <<= 1)
            acc[k] += __shfl_xor(acc[k], off, 64);
    }

    if (sub == 0) {
        float add = (wbp != nullptr && wbp[0] != 0) ? (1.0f - acc[7]) : 0.0f;
        size_t rb = (size_t)OFF_RGB + (size_t)g * 3;
        out[rb + 0] = acc[0] + add;
        out[rb + 1] = acc[1] + add;
        out[rb + 2] = acc[2] + add;
        size_t pb = (size_t)OFF_PT + (size_t)g * 3;
        out[pb + 0] = acc[3];
        out[pb + 1] = acc[4];
        out[pb + 2] = acc[5];
        float cd = acc[6];
        if (cd != cd) cd = __int_as_float(0x7f800000);   // nan_to_num -> +inf
        float dmin = __uint_as_float(mm[0]);
        float dmax = __uint_as_float(~mm[1]);
        cd = fminf(fmaxf(cd, dmin), dmax);               // jnp.clip(global min/max)
        out[OFF_DEPTH + g] = cd;
        out[OFF_TAU + g]   = tau;
    }
}

extern "C" void kernel_launch(void* const* d_in, const int* in_sizes, int n_in,
                              void* d_out, int out_size, void* d_ws, size_t ws_size,
                              hipStream_t stream) {
    const float* colors = (const float*)d_in[0];
    const float* dens   = (const float*)d_in[1];
    const float* deps   = (const float*)d_in[2];
    const float* coords = (const float*)d_in[3];
    const int*   wb     = (n_in > 4) ? (const int*)d_in[4] : nullptr;
    float* out = (float*)d_out;
    unsigned* mm = (unsigned*)d_ws;

    // Both slots init 0xFFFFFFFF (min slot: uint-max; max slot stores ~bits).
    hipMemsetAsync(mm, 0xFF, 8, stream);
    depth_minmax_sorted<<<NRAYS / 256, 256, 0, stream>>>(deps, mm);
    raymarch<<<NRAYS / 16, 256, 0, stream>>>(colors, dens, deps, coords, wb, mm, out);
}

// Round 6
// 236.909 us; speedup vs baseline: 1.0325x; 1.0325x over previous
//
#include <hip/hip_runtime.h>

// Problem constants: B=4, R=16384, S=96
#define NRAYS 65536
#define NS    96
#define NI    95

// Output layout (FP32, outputs concatenated flat in return order):
//   composite_rgb   : [0,        196608)
//   composite_depth : [196608,   262144)
//   weights         : [262144,   6488064)
//   composite_point : [6488064,  6684672)
//   tau             : [6684672,  6750208)
#define OFF_RGB   0
#define OFF_DEPTH 196608
#define OFF_W     262144
#define OFF_PT    6488064
#define OFF_TAU   6684672

// ---------------------------------------------------------------------------
// Global depth min/max. depths are jnp.sort()ed along the sample axis by
// construction, so global min = min over rays of sample 0, global max = max
// over rays of sample 95. Max encoded as atomicMin of ~bits (depths >= 0),
// so both ws slots init 0xFFFFFFFF -> single 8-byte memset.
// ---------------------------------------------------------------------------
__global__ void depth_minmax_sorted(const float* __restrict__ deps, unsigned* ws) {
    const int t = blockIdx.x * blockDim.x + threadIdx.x;   // grid covers exactly NRAYS
    float lo = deps[(size_t)t * NS];
    float hi = deps[(size_t)t * NS + (NS - 1)];
    #pragma unroll
    for (int off = 32; off; off >>= 1) {
        lo = fminf(lo, __shfl_xor(lo, off, 64));
        hi = fmaxf(hi, __shfl_xor(hi, off, 64));
    }
    if ((threadIdx.x & 63) == 0) {
        atomicMin(&ws[0], __float_as_uint(lo));
        atomicMin(&ws[1], ~__float_as_uint(hi));   // max via inverted-bit min
    }
}

__device__ __forceinline__ float softplus_fast(float x) {
    // softplus = max(x,0) + log(1 + exp(-|x|)); __logf/__expf are single
    // v_log/v_exp instrs (~1e-6 rel err; tolerance headroom ~6x).
    return fmaxf(x, 0.0f) + __logf(1.0f + __expf(-fabsf(x)));
}

// Fire-and-forget global->LDS DMA, 16 B per active lane, dest = uniform LDS
// base + lane*16 (linear). No destination VGPRs -> the compiler CANNOT sink
// or rematerialize it (what killed R4's and R5's register-staged prefetch).
__device__ __forceinline__ void gload_lds16(const float* gp, float* lp) {
    __builtin_amdgcn_global_load_lds(
        (const __attribute__((address_space(1))) void*)gp,
        (__attribute__((address_space(3))) void*)lp,
        16, 0, 0);
}

// ---------------------------------------------------------------------------
// R6: async LDS staging. R5 post-mortem: VGPR stayed 36 and FETCH grew
// +27 MB -> compiler re-loaded per phase; register-resident MLP is
// un-forceable. This version uses global_load_lds (no dest regs, cannot be
// sunk): each wave issues its full 9 KB of colors+coords DMA up front into
// a wave-private LDS region, computes alpha/scan from directly-loaded d/n
// (R1-proven 24 B-stride consumer-layout float2) while the DMA flies, then
// one s_waitcnt vmcnt(0) and pure-LDS consumption. d/n loads are issued
// FIRST so their auto-wait is a counted vmcnt(10), not a drain. No
// barriers; weights keep the R1/R2/R4-proven direct dword scatter.
// Per-CU in-flight: 16 waves x 9 KB = 144 KB >> Little's-law need.
// ---------------------------------------------------------------------------
__launch_bounds__(256, 4)
__global__ void raymarch(const float* __restrict__ colors,
                         const float* __restrict__ dens,
                         const float* __restrict__ deps,
                         const float* __restrict__ coords,
                         const int* __restrict__ wbp,
                         const unsigned* __restrict__ mm,
                         float* __restrict__ out) {
    __shared__ float sbuf[4 * 2304];   // 36864 B: per wave [c:1152 | p:1152]

    const int tid  = threadIdx.x;
    const int lane = tid & 63;
    const int wv   = tid >> 6;                    // wave in block (0..3)
    const int sub  = lane & 15;                   // position within ray group
    const int r4   = lane >> 4;                   // ray within wave (0..3)
    const int g    = blockIdx.x * 16 + wv * 4 + r4;   // global ray id
    const size_t rb0 = (size_t)blockIdx.x * 16 + wv * 4;  // first ray of wave

    // ---- d/n: direct consumer-layout loads, issued FIRST (counted wait) ----
    const float2* dq = (const float2*)(deps + (size_t)g * NS + 6 * sub);
    const float2* nq = (const float2*)(dens + (size_t)g * NS + 6 * sub);
    float2 dv0 = dq[0], dv1 = dq[1], dv2 = dq[2];
    float2 nv0 = nq[0], nv1 = nq[1], nv2 = nq[2];

    __builtin_amdgcn_sched_barrier(0);   // keep d/n loads above the DMA issue

    // ---- c/p: 10 async DMA instrs -> wave-private LDS (9216 B) ----
    float* cl = sbuf + wv * 2304;        // colors: floats [0,1152)
    float* pl = cl + 1152;               // coords: floats [1152,2304)
    {
        const float* cg = colors + rb0 * (NS * 3);
        const float* pg = coords + rb0 * (NS * 3);
        #pragma unroll
        for (int k = 0; k < 4; ++k) gload_lds16(cg + 4 * lane + 256 * k, cl + 256 * k);
        #pragma unroll
        for (int k = 0; k < 4; ++k) gload_lds16(pg + 4 * lane + 256 * k, pl + 256 * k);
        if (lane < 32) {                 // 128-float tails (32 lanes x 16 B)
            gload_lds16(cg + 1024 + 4 * lane, cl + 1024);
            gload_lds16(pg + 1024 + 4 * lane, pl + 1024);
        }
    }

    // ---- unpack d/n; neighbor sample via shuffle (R1-proven pattern) ----
    float d[6], n[6];
    d[0] = dv0.x; d[1] = dv0.y; d[2] = dv1.x; d[3] = dv1.y; d[4] = dv2.x; d[5] = dv2.y;
    n[0] = nv0.x; n[1] = nv0.y; n[2] = nv1.x; n[3] = nv1.y; n[4] = nv2.x; n[5] = nv2.y;
    const int nsrc = (lane & 48) | ((sub + 1) & 15);   // sub15 -> dummy
    float d6 = __shfl(d[0], nsrc, 64);
    float n6 = __shfl(n[0], nsrc, 64);

    // ---- alpha / transmittance factors (DMA still in flight under this) ----
    float a[6], f[6];
    #pragma unroll
    for (int i = 0; i < 6; ++i) {
        float dn1 = (i < 5) ? d[i+1] : d6;
        float nn1 = (i < 5) ? n[i+1] : n6;
        float E = __expf(-softplus_fast(0.5f * (n[i] + nn1)) * (dn1 - d[i]));
        const bool valid = (i < 5) || (sub < 15);    // compile-time except i==5
        a[i] = valid ? (1.0f - E) : 0.0f;
        f[i] = valid ? (E + 1e-10f) : 1.0f;
    }

    // ---- inclusive scan of per-lane factor product over the 16-lane group ----
    float incl = ((f[0] * f[1]) * (f[2] * f[3])) * (f[4] * f[5]);
    #pragma unroll
    for (int off = 1; off < 16; off <<= 1) {
        float t = __shfl_up(incl, off, 16);
        if (sub >= off) incl *= t;
    }
    float excl = __shfl_up(incl, 1, 16);
    if (sub == 0) excl = 1.0f;

    // ---- DMA landed by now; single drain, then pure-LDS consumption ----
    asm volatile("s_waitcnt vmcnt(0)" ::: "memory");

    float c[18], p[18], cn0, cn1, cn2, pn0, pn1, pn2;
    {
        const float2* qc = (const float2*)(cl + r4 * 288 + 18 * sub);
        const float2* qp = (const float2*)(pl + r4 * 288 + 18 * sub);
        #pragma unroll
        for (int j = 0; j < 9; ++j) { float2 v = qc[j]; c[2*j] = v.x; c[2*j+1] = v.y; }
        #pragma unroll
        for (int j = 0; j < 9; ++j) { float2 v = qp[j]; p[2*j] = v.x; p[2*j+1] = v.y; }
        const int noff = (sub < 15) ? 18 * (sub + 1) : 0;   // dummy for sub 15
        cn0 = cl[r4 * 288 + noff + 0];
        cn1 = cl[r4 * 288 + noff + 1];
        cn2 = cl[r4 * 288 + noff + 2];
        pn0 = pl[r4 * 288 + noff + 0];
        pn1 = pl[r4 * 288 + noff + 1];
        pn2 = pl[r4 * 288 + noff + 2];
    }

    // ---- weights (direct scatter store, L2-merged) + composite partials ----
    float acc[8];
    #pragma unroll
    for (int k = 0; k < 8; ++k) acc[k] = 0.0f;
    float t = excl;          // t == trans[6*sub + i] at top of iteration i
    float tauc = 0.0f;
    const size_t wb = (size_t)OFF_W + (size_t)g * NI + 6 * sub;
    #pragma unroll
    for (int i = 0; i < 6; ++i) {
        float w = a[i] * t;
        if (i < 5 || sub < 15) out[wb + i] = w;      // weights output
        float dn1 = (i < 5) ? d[i+1] : d6;
        float dm  = 0.5f * (d[i] + dn1);
        float cmx = 0.5f * (c[3*i+0] + ((i < 5) ? c[3*i+3] : cn0));
        float cmy = 0.5f * (c[3*i+1] + ((i < 5) ? c[3*i+4] : cn1));
        float cmz = 0.5f * (c[3*i+2] + ((i < 5) ? c[3*i+5] : cn2));
        float pmx = 0.5f * (p[3*i+0] + ((i < 5) ? p[3*i+3] : pn0));
        float pmy = 0.5f * (p[3*i+1] + ((i < 5) ? p[3*i+4] : pn1));
        float pmz = 0.5f * (p[3*i+2] + ((i < 5) ? p[3*i+5] : pn2));
        acc[0] += w * cmx;  acc[1] += w * cmy;  acc[2] += w * cmz;
        acc[3] += w * pmx;  acc[4] += w * pmy;  acc[5] += w * pmz;
        acc[6] += w * dm;   acc[7] += w;
        if (i == 4) tauc = t;      // lane sub==15, i==4: t == trans[94] == tau
        t *= f[i];
    }
    float tau = __shfl(tauc, (lane & 48) | 15, 64);

    // ---- reduce 8 accumulators across the 16-lane group (4 butterfly steps) ----
    #pragma unroll
    for (int k = 0; k < 8; ++k) {
        #pragma unroll
        for (int off = 1; off < 16; off <<= 1)
            acc[k] += __shfl_xor(acc[k], off, 64);
    }

    if (sub == 0) {
        float add = (wbp != nullptr && wbp[0] != 0) ? (1.0f - acc[7]) : 0.0f;
        size_t rb = (size_t)OFF_RGB + (size_t)g * 3;
        out[rb + 0] = acc[0] + add;
        out[rb + 1] = acc[1] + add;
        out[rb + 2] = acc[2] + add;
        size_t pb = (size_t)OFF_PT + (size_t)g * 3;
        out[pb + 0] = acc[3];
        out[pb + 1] = acc[4];
        out[pb + 2] = acc[5];
        float cd = acc[6];
        if (cd != cd) cd = __int_as_float(0x7f800000);   // nan_to_num -> +inf
        float dmin = __uint_as_float(mm[0]);
        float dmax = __uint_as_float(~mm[1]);
        cd = fminf(fmaxf(cd, dmin), dmax);               // jnp.clip(global min/max)
        out[OFF_DEPTH + g] = cd;
        out[OFF_TAU + g]   = tau;
    }
}

extern "C" void kernel_launch(void* const* d_in, const int* in_sizes, int n_in,
                              void* d_out, int out_size, void* d_ws, size_t ws_size,
                              hipStream_t stream) {
    const float* colors = (const float*)d_in[0];
    const float* dens   = (const float*)d_in[1];
    const float* deps   = (const float*)d_in[2];
    const float* coords = (const float*)d_in[3];
    const int*   wb     = (n_in > 4) ? (const int*)d_in[4] : nullptr;
    float* out = (float*)d_out;
    unsigned* mm = (unsigned*)d_ws;

    // Both slots init 0xFFFFFFFF (min slot: uint-max; max slot stores ~bits).
    hipMemsetAsync(mm, 0xFF, 8, stream);
    depth_minmax_sorted<<<NRAYS / 256, 256, 0, stream>>>(deps, mm);
    raymarch<<<NRAYS / 16, 256, 0, stream>>>(colors, dens, deps, coords, wb, mm, out);
}